// Round 11
// baseline (225.297 us; speedup 1.0000x reference)
//
#include <hip/hip_runtime.h>

#define F 128
#define LEAK 0.2f

typedef __attribute__((ext_vector_type(8))) short bf16x8;
typedef __attribute__((ext_vector_type(4))) float f32x4;

union FragU { bf16x8 v; unsigned u[4]; };

__device__ inline unsigned f2bf(float f) {
  unsigned u = __float_as_uint(f);
  return (u + 0x7FFFu + ((u >> 16) & 1u)) >> 16;  // RNE
}
__device__ inline unsigned packbf(float lo, float hi) {
  return f2bf(lo) | (f2bf(hi) << 16);
}
__device__ inline float bflo(unsigned u) { return __uint_as_float(u << 16); }
__device__ inline float bfhi(unsigned u) { return __uint_as_float(u & 0xFFFF0000u); }

// fetch (src,dst) for concat([edges, self-loops]) edge i
__device__ inline void edge_sd(const int* ei, int i, int E, int is64, int& s, int& d) {
  if (i < E) {
    if (is64) {
      const long long* e64 = (const long long*)ei;
      s = (int)e64[i]; d = (int)e64[E + i];
    } else {
      s = ei[i]; d = ei[E + i];
    }
  } else {
    s = d = i - E;
  }
}

// ---------- init: zero deg/cursor, probe edge dtype, AND prep weight transposes ----------
// blocks [0, nzb): zero+detect; blocks [nzb, nzb+96): W/W1 -> bf16 [n][k]
__global__ void init_kernel(const int* ei, int* flag, int* deg, int* cursor,
                            const float* __restrict__ W,
                            const float* __restrict__ W1, unsigned* wt,
                            unsigned* w1t, int N, int nzb) {
  if ((int)blockIdx.x < nzb) {
    int i = blockIdx.x * blockDim.x + threadIdx.x;
    if (i < N) { deg[i] = 0; cursor[i] = 0; }
    if (blockIdx.x == 0) {
      __shared__ int any;
      if (threadIdx.x == 0) any = 0;
      __syncthreads();
      for (int k = threadIdx.x; k < 1024; k += blockDim.x)
        if (ei[2 * k + 1] != 0) any = 1;
      __syncthreads();
      if (threadIdx.x == 0) *flag = (any == 0) ? 1 : 0;  // 1 => int64
    }
    return;
  }
  int i = (blockIdx.x - nzb) * 256 + threadIdx.x;
  if (i < 128 * 64) {
    int n = i & 127, k2 = i >> 7;
    wt[n * 64 + k2] =
        packbf(W[(size_t)(2 * k2) * 128 + n], W[(size_t)(2 * k2 + 1) * 128 + n]);
  }
  int j = i - 128 * 64;
  if (j >= 0 && j < 128 * 128) {
    int n = j & 127, k2 = j >> 7;
    w1t[n * 128 + k2] = packbf(W1[(size_t)(2 * k2) * 128 + n],
                               W1[(size_t)(2 * k2 + 1) * 128 + n]);
  }
}

// ---------- count in-degree (incl self-loops) ----------
__global__ void count_kernel(const int* ei, int* deg, const int* flag, int E, int N) {
  int i = blockIdx.x * blockDim.x + threadIdx.x;
  if (i >= E + N) return;
  int s, d;
  edge_sd(ei, i, E, *flag, s, d);
  atomicAdd(&deg[d], 1);
}

// ---------- scan phase 1: per-1024-chunk sums ----------
__global__ void scan1_kernel(const int* deg, int* partial, int N) {
  __shared__ int ts[256];
  int b = blockIdx.x, t = threadIdx.x;
  int base = b * 1024 + t * 4;
  int s = 0;
#pragma unroll
  for (int k = 0; k < 4; ++k) s += (base + k < N) ? deg[base + k] : 0;
  ts[t] = s;
  __syncthreads();
  for (int o = 128; o > 0; o >>= 1) {
    if (t < o) ts[t] += ts[t + o];
    __syncthreads();
  }
  if (t == 0) partial[b] = ts[0];
}

// ---------- scan phase 2+3 merged: each block re-scans chunk sums locally ----------
__global__ void scan3_kernel(const int* deg, const int* partial,
                             int* row_start, int nchunks, int N) {
  __shared__ int ts[256];
  __shared__ int cs[256];
  int b = blockIdx.x, t = threadIdx.x;

  int pv = (t < nchunks) ? partial[t] : 0;
  cs[t] = pv;
  __syncthreads();
  for (int o = 1; o < 256; o <<= 1) {
    int add = (t >= o) ? cs[t - o] : 0;
    __syncthreads();
    cs[t] += add;
    __syncthreads();
  }
  if (b == 0 && t == 0) row_start[N] = cs[nchunks - 1];  // total = E + N
  int chunk_off_b = cs[b] - partial[b];  // exclusive prefix of chunk b

  int base = b * 1024 + t * 4;
  int v[4];
#pragma unroll
  for (int k = 0; k < 4; ++k) v[k] = (base + k < N) ? deg[base + k] : 0;
  int p1 = v[0], p2 = p1 + v[1], p3 = p2 + v[2], sum = p3 + v[3];
  ts[t] = sum;
  __syncthreads();
  for (int o = 1; o < 256; o <<= 1) {
    int add = (t >= o) ? ts[t - o] : 0;
    __syncthreads();
    ts[t] += add;
    __syncthreads();
  }
  int off = chunk_off_b + ts[t] - sum;
  int ex[4] = {0, p1, p2, p3};
#pragma unroll
  for (int k = 0; k < 4; ++k)
    if (base + k < N) row_start[base + k] = off + ex[k];
}

// ---------- fill sorted_src buckets ----------
__global__ void fill_kernel(const int* ei, const int* row_start, int* cursor,
                            int* sorted_src, const int* flag, int E, int N) {
  int i = blockIdx.x * blockDim.x + threadIdx.x;
  if (i >= E + N) return;
  int s, d;
  edge_sd(ei, i, E, *flag, s, d);
  int p = atomicAdd(&cursor[d], 1);
  sorted_src[row_start[d] + p] = s;
}

// ---------- xp = x @ W via bf16 MFMA; B staged in LDS; xp bf16 via 2-phase LDS bounce ----------
// 512 threads = 8 waves, wave owns 16 rows; grid-stride over 128-row tiles.
// LDS 48KB -> 3 blocks/CU.
__global__ __launch_bounds__(512) void gemm_xp_kernel(
    const float* __restrict__ x, const unsigned* __restrict__ wt,
    const float* __restrict__ a_src, const float* __restrict__ a_dst,
    unsigned short* __restrict__ xp, float* __restrict__ alpha_s,
    float* __restrict__ alpha_d, int N, int ntiles) {
  __shared__ char WtL[128 * 256];   // [n][k] bf16 swizzled, 32KB
  __shared__ char stage[8 * 2048];  // per-wave 8 rows x 256B, swizzled (16KB)
  const int tid = threadIdx.x;
  const int w = tid >> 6, l = tid & 63;
  const int lr = l & 15, lg = l >> 4;
  char* st = stage + w * 2048;

  // stage whole Wt (bf16 [n][128k]) into LDS, swizzled
  for (int c = tid; c < 2048; c += 512) {
    int n = c >> 4, q = c & 15;
    uint4 v = *(const uint4*)(wt + n * 64 + q * 4);
    *(uint4*)(WtL + n * 256 + ((q * 16) ^ ((n & 7) << 4))) = v;
  }

  float asv[8], adv[8];
#pragma unroll
  for (int f = 0; f < 8; ++f) {
    asv[f] = a_src[f * 16 + lr];
    adv[f] = a_dst[f * 16 + lr];
  }
  __syncthreads();

  for (int t = blockIdx.x; t < ntiles; t += gridDim.x) {
    const int rbase = t * 128 + w * 16;
    const int rc = min(rbase + lr, N - 1);
    const float* xrow = x + (size_t)rc * 128;

    FragU a[4];
#pragma unroll
    for (int ks = 0; ks < 4; ++ks) {
      float4 p0 = *(const float4*)(xrow + ks * 32 + lg * 8);
      float4 p1 = *(const float4*)(xrow + ks * 32 + lg * 8 + 4);
      a[ks].u[0] = packbf(p0.x, p0.y); a[ks].u[1] = packbf(p0.z, p0.w);
      a[ks].u[2] = packbf(p1.x, p1.y); a[ks].u[3] = packbf(p1.z, p1.w);
    }

    f32x4 acc[8];
#pragma unroll
    for (int f = 0; f < 8; ++f) acc[f] = (f32x4){0.f, 0.f, 0.f, 0.f};

#pragma unroll
    for (int ks = 0; ks < 4; ++ks) {
#pragma unroll
      for (int f = 0; f < 8; ++f) {
        int n = f * 16 + lr;
        FragU bfr;
        bfr.v = *(const bf16x8*)(WtL + n * 256 +
                                 ((ks * 64 + lg * 16) ^ ((n & 7) << 4)));
        acc[f] = __builtin_amdgcn_mfma_f32_16x16x32_bf16(a[ks].v, bfr.v,
                                                         acc[f], 0, 0, 0);
      }
    }

    // fused alpha reductions (fp32, from acc directly)
#pragma unroll
    for (int r = 0; r < 4; ++r) {
      int orow = rbase + lg * 4 + r;
      float ps = 0.f, pd = 0.f;
#pragma unroll
      for (int f = 0; f < 8; ++f) {
        ps = fmaf(acc[f][r], asv[f], ps);
        pd = fmaf(acc[f][r], adv[f], pd);
      }
#pragma unroll
      for (int m = 1; m < 16; m <<= 1) {
        ps += __shfl_xor(ps, m);
        pd += __shfl_xor(pd, m);
      }
      if (orow < N && lr == 0) alpha_s[orow] = ps;
      if (orow < N && lr == 1) alpha_d[orow] = pd;
    }

    // acc -> xp via 2-phase per-wave LDS bounce (8 rows/phase; wave-local,
    // in-order DS ops make the WAR on phase reuse safe)
#pragma unroll
    for (int ph = 0; ph < 2; ++ph) {
      if ((lg >> 1) == ph) {
#pragma unroll
        for (int f = 0; f < 8; ++f) {
          int colb = (f * 16 + lr) * 2;
#pragma unroll
          for (int r = 0; r < 4; ++r) {
            int row = (lg & 1) * 4 + r;  // 0..7 within phase
            *(unsigned short*)(st + row * 256 + (colb ^ ((row & 7) << 4))) =
                (unsigned short)f2bf(acc[f][r]);
          }
        }
      }
#pragma unroll
      for (int it = 0; it < 2; ++it) {
        int off = it * 1024 + l * 16;
        int row = off >> 8, colb = off & 255;
        int4 v = *(const int4*)(st + row * 256 + (colb ^ ((row & 7) << 4)));
        int grow = rbase + ph * 8 + row;
        if (grow < N) *(int4*)((char*)xp + (size_t)grow * 256 + colb) = v;
      }
    }
  }
}

// ---------- gather: one wave per dst node; in-register softmax; half-wave 2-edge
// feature accumulation. Writes fp32 out0 (half 0) AND bf16 relu(xemb) (half 1). ----------
__global__ __launch_bounds__(256) void gather_kernel(
    const int* __restrict__ row_start, const int* __restrict__ sorted_src,
    const float* __restrict__ alpha_s, const float* __restrict__ alpha_d,
    const unsigned short* __restrict__ xp, const float* __restrict__ bias,
    float* __restrict__ out0, unsigned short* __restrict__ xe16, int N) {
  int wid = blockIdx.x * 4 + (threadIdx.x >> 6);
  int lane = threadIdx.x & 63;
  if (wid >= N) return;
  int rs = row_start[wid], re = row_start[wid + 1];
  int deg = re - rs;
  float ad = alpha_d[wid];

  if (deg <= 64) {
    const int half = lane >> 5;  // which edge of the pair
    const int hl = lane & 31;    // lane within half: features hl*4..+3

    // lane j owns edge j: score, wave softmax (w_reg = 0 for lanes >= deg)
    int src_reg = 0;
    float e = -INFINITY;
    if (lane < deg) {
      src_reg = sorted_src[rs + lane];
      e = alpha_s[src_reg] + ad;
      e = (e >= 0.f) ? e : LEAK * e;
    }
    float m = e;
#pragma unroll
    for (int o = 32; o > 0; o >>= 1) m = fmaxf(m, __shfl_xor(m, o));
    float ex = (lane < deg) ? expf(e - m) : 0.f;
    float lsum = ex;
#pragma unroll
    for (int o = 32; o > 0; o >>= 1) lsum += __shfl_xor(lsum, o);
    float w_reg = ex / lsum;

    float c0 = 0.f, c1 = 0.f, c2 = 0.f, c3 = 0.f;
    int j = 0;
    for (; j + 3 < deg; j += 4) {  // 4 edges: 2 per half, 2 loads in flight
      int jj0 = j + half, jj1 = j + 2 + half;
      int s0 = __shfl(src_reg, jj0), s1 = __shfl(src_reg, jj1);
      float w0 = __shfl(w_reg, jj0), w1 = __shfl(w_reg, jj1);
      uint2 u0 = *(const uint2*)(xp + (size_t)s0 * 128 + hl * 4);
      uint2 u1 = *(const uint2*)(xp + (size_t)s1 * 128 + hl * 4);
      c0 = fmaf(w0, bflo(u0.x), c0); c1 = fmaf(w0, bfhi(u0.x), c1);
      c2 = fmaf(w0, bflo(u0.y), c2); c3 = fmaf(w0, bfhi(u0.y), c3);
      c0 = fmaf(w1, bflo(u1.x), c0); c1 = fmaf(w1, bfhi(u1.x), c1);
      c2 = fmaf(w1, bflo(u1.y), c2); c3 = fmaf(w1, bfhi(u1.y), c3);
    }
    for (; j < deg; j += 2) {  // tail: jj <= 63 always (j even, j < deg <= 64)
      int jj = j + half;
      int s0 = __shfl(src_reg, jj);
      float w0 = __shfl(w_reg, jj);  // 0 when jj >= deg
      uint2 u0 = *(const uint2*)(xp + (size_t)s0 * 128 + hl * 4);
      c0 = fmaf(w0, bflo(u0.x), c0); c1 = fmaf(w0, bfhi(u0.x), c1);
      c2 = fmaf(w0, bflo(u0.y), c2); c3 = fmaf(w0, bfhi(u0.y), c3);
    }
    // combine halves; half 0 stores fp32 out0, half 1 stores bf16 relu
    c0 += __shfl_xor(c0, 32); c1 += __shfl_xor(c1, 32);
    c2 += __shfl_xor(c2, 32); c3 += __shfl_xor(c3, 32);
    float4 bv = *(const float4*)(bias + hl * 4);
    c0 += bv.x; c1 += bv.y; c2 += bv.z; c3 += bv.w;
    if (half == 0) {
      *(float4*)(out0 + (size_t)wid * F + hl * 4) = make_float4(c0, c1, c2, c3);
    } else {
      unsigned lo = packbf(fmaxf(c0, 0.f), fmaxf(c1, 0.f));
      unsigned hi = packbf(fmaxf(c2, 0.f), fmaxf(c3, 0.f));
      *(uint2*)(xe16 + (size_t)wid * 128 + hl * 4) = make_uint2(lo, hi);
    }
  } else {
    // rare fallback: strided softmax stats, then uniform per-edge loop
    float a0 = 0.f, a1 = 0.f;
    float m = -INFINITY;
    for (int j = lane; j < deg; j += 64) {
      float e = alpha_s[sorted_src[rs + j]] + ad;
      e = (e >= 0.f) ? e : LEAK * e;
      m = fmaxf(m, e);
    }
#pragma unroll
    for (int o = 32; o > 0; o >>= 1) m = fmaxf(m, __shfl_xor(m, o));
    float lsum = 0.f;
    for (int j = lane; j < deg; j += 64) {
      float e = alpha_s[sorted_src[rs + j]] + ad;
      e = (e >= 0.f) ? e : LEAK * e;
      lsum += expf(e - m);
    }
#pragma unroll
    for (int o = 32; o > 0; o >>= 1) lsum += __shfl_xor(lsum, o);
    float inv = 1.f / lsum;
    for (int j = 0; j < deg; ++j) {
      int s0 = sorted_src[rs + j];
      float e = alpha_s[s0] + ad;
      e = (e >= 0.f) ? e : LEAK * e;
      float w0 = expf(e - m) * inv;
      unsigned u0 = *(const unsigned*)(xp + (size_t)s0 * 128 + lane * 2);
      a0 = fmaf(w0, bflo(u0), a0); a1 = fmaf(w0, bfhi(u0), a1);
    }
    float2 bv = *(const float2*)(bias + lane * 2);
    a0 += bv.x; a1 += bv.y;
    *(float2*)(out0 + (size_t)wid * F + lane * 2) = make_float2(a0, a1);
    *(unsigned*)(xe16 + (size_t)wid * 128 + lane * 2) =
        packbf(fmaxf(a0, 0.f), fmaxf(a1, 0.f));
  }
}

// ---------- fused MLP via bf16 MFMA; W1 staged per-K-QUARTER in LDS (16KB) ----------
// 512 threads = 8 waves; 128-row tiles grid-stride; wave w owns rows w*16..+15.
// LDS 52KB -> 3 blocks/CU. Second K-half reads pre-relu'd bf16 xe16 directly.
__global__ __launch_bounds__(512) void mlp_kernel(
    const float* __restrict__ x, const unsigned short* __restrict__ xe16,
    const unsigned* __restrict__ w1t, const float* __restrict__ b1,
    const float* __restrict__ W2, const float* __restrict__ b2,
    const float* __restrict__ W3, const float* __restrict__ b3,
    float* __restrict__ out2, int N, int ntiles) {
  __shared__ char W1L[128 * 128];  // [n][one K-quarter] bf16 swizzled, 16KB
  __shared__ char W2t[16 * 256];   // [n][k] bf16 swizzled, 4KB
  __shared__ char h1s[128 * 256];  // [row][k] bf16 swizzled, 32KB (per-wave regions)
  const int tid = threadIdx.x;

  for (int idx = tid; idx < 16 * 64; idx += 512) {
    int n = idx & 15, k = (idx >> 4) * 2;
    unsigned p = packbf(W2[(size_t)k * 16 + n], W2[(size_t)(k + 1) * 16 + n]);
    *(unsigned*)(W2t + n * 256 + ((k * 2) ^ ((n & 7) << 4))) = p;
  }

  const int w = tid >> 6, l = tid & 63;
  const int lr = l & 15, lg = l >> 4;
  float b1v[8];
#pragma unroll
  for (int f = 0; f < 8; ++f) b1v[f] = b1[f * 16 + lr];
  const float b2v = b2[lr];
  const float w30 = W3[lr * 2 + 0], w31 = W3[lr * 2 + 1];
  const float b30 = b3[0], b31 = b3[1];

  for (int t = blockIdx.x; t < ntiles; t += gridDim.x) {
    const int rbase = t * 128 + w * 16;
    const int rc = min(rbase + lr, N - 1);
    const float* xrow = x + (size_t)rc * 128;
    const unsigned short* erow = xe16 + (size_t)rc * 128;

    f32x4 acc[8];
#pragma unroll
    for (int f = 0; f < 8; ++f) acc[f] = (f32x4){0.f, 0.f, 0.f, 0.f};

#pragma unroll
    for (int q = 0; q < 4; ++q) {
      // stage K-quarter q of W1 (64 k's = 32 dwords per n, 16KB)
      __syncthreads();  // prev quarter's readers done
      for (int c = tid; c < 1024; c += 512) {
        int n = c >> 3, j = (c & 7) * 4;
        uint4 v = *(const uint4*)(w1t + n * 128 + q * 32 + j);
        *(uint4*)(W1L + n * 128 + ((j * 4) ^ ((n & 7) << 4))) = v;
      }
      __syncthreads();

      // A fragments for this quarter (q<2: x fp32->bf16; q>=2: xe16 direct)
      FragU a[2];
#pragma unroll
      for (int ks = 0; ks < 2; ++ks) {
        if (q < 2) {
          const float* src = xrow + q * 64 + ks * 32 + lg * 8;
          float4 p0 = *(const float4*)(src);
          float4 p1 = *(const float4*)(src + 4);
          a[ks].u[0] = packbf(p0.x, p0.y); a[ks].u[1] = packbf(p0.z, p0.w);
          a[ks].u[2] = packbf(p1.x, p1.y); a[ks].u[3] = packbf(p1.z, p1.w);
        } else {
          a[ks].v = *(const bf16x8*)(erow + (q - 2) * 64 + ks * 32 + lg * 8);
        }
      }

#pragma unroll
      for (int ks = 0; ks < 2; ++ks) {
#pragma unroll
        for (int f = 0; f < 8; ++f) {
          int n = f * 16 + lr;
          FragU bfr;
          bfr.v = *(const bf16x8*)(W1L + n * 128 +
                                   ((ks * 64 + lg * 16) ^ ((n & 7) << 4)));
          acc[f] = __builtin_amdgcn_mfma_f32_16x16x32_bf16(a[ks].v, bfr.v,
                                                           acc[f], 0, 0, 0);
        }
      }
    }

    // h1 = relu(acc + b1) -> per-wave LDS region (bf16, swizzled)
#pragma unroll
    for (int f = 0; f < 8; ++f) {
      int col = f * 16 + lr;
#pragma unroll
      for (int r = 0; r < 4; ++r) {
        int hrow = w * 16 + lg * 4 + r;
        float v = fmaxf(acc[f][r] + b1v[f], 0.f);
        *(unsigned short*)(h1s + hrow * 256 + ((col * 2) ^ ((hrow & 7) << 4))) =
            (unsigned short)f2bf(v);
      }
    }

    // ---- layer 2: wave's 16 rows x 16 cols, K=128 (wave-local LDS) ----
    f32x4 acc2 = (f32x4){0.f, 0.f, 0.f, 0.f};
#pragma unroll
    for (int ks = 0; ks < 4; ++ks) {
      int hrow = w * 16 + lr;
      FragU af, bfr;
      af.v = *(const bf16x8*)(h1s + hrow * 256 +
                              ((ks * 64 + lg * 16) ^ ((hrow & 7) << 4)));
      bfr.v = *(const bf16x8*)(W2t + lr * 256 +
                               ((ks * 64 + lg * 16) ^ ((lr & 7) << 4)));
      acc2 = __builtin_amdgcn_mfma_f32_16x16x32_bf16(af.v, bfr.v, acc2, 0, 0, 0);
    }

    // ---- layer 3 + sigmoid: quarter-wave shuffle reduce over 16 cols ----
#pragma unroll
    for (int r = 0; r < 4; ++r) {
      float h2 = fmaxf(acc2[r] + b2v, 0.f);
      float t0 = h2 * w30, t1 = h2 * w31;
#pragma unroll
      for (int m = 1; m < 16; m <<= 1) {
        t0 += __shfl_xor(t0, m);
        t1 += __shfl_xor(t1, m);
      }
      int orow = rbase + lg * 4 + r;
      if (orow < N && lr < 2) {
        float s = (lr == 0) ? (t0 + b30) : (t1 + b31);
        out2[(size_t)orow * 2 + lr] = 1.f / (1.f + expf(-s));
      }
    }
  }
}

// ---------- launch ----------
extern "C" void kernel_launch(void* const* d_in, const int* in_sizes, int n_in,
                              void* d_out, int out_size, void* d_ws,
                              size_t ws_size, hipStream_t stream) {
  const float* x     = (const float*)d_in[0];
  const int*   ei    = (const int*)d_in[1];
  const float* W     = (const float*)d_in[2];
  const float* a_src = (const float*)d_in[3];
  const float* a_dst = (const float*)d_in[4];
  const float* bias  = (const float*)d_in[5];
  const float* W1    = (const float*)d_in[6];
  const float* b1    = (const float*)d_in[7];
  const float* W2    = (const float*)d_in[8];
  const float* b2    = (const float*)d_in[9];
  const float* W3    = (const float*)d_in[10];
  const float* b3    = (const float*)d_in[11];

  const int N = in_sizes[0] / F;
  const int E = in_sizes[1] / 2;
  const int EN = E + N;
  const int nchunks = (N + 1023) / 1024;
  const int ntiles = (N + 127) / 128;
  const int nzb = (N + 255) / 256;

  float* ws = (float*)d_ws;
  unsigned short* xp   = (unsigned short*)ws;       // N*128 bf16 (= N*64 floats)
  unsigned short* xe16 = xp + (size_t)N * 128;      // N*128 bf16 relu(xemb)
  float* alpha_s  = ws + (size_t)N * 128;           // N  (after 2 bf16 arrays)
  float* alpha_d  = alpha_s + N;                    // N
  unsigned* wt    = (unsigned*)(alpha_d + N);       // 128*64
  unsigned* w1t   = wt + 128 * 64;                  // 128*128
  int* deg        = (int*)(w1t + 128 * 128);        // N
  int* row_start  = deg + N;                        // N+1
  int* cursor     = row_start + N + 1;              // N
  int* partial    = cursor + N;                     // 256
  int* sorted_src = partial + 256;                  // EN
  int* flag       = sorted_src + EN;                // 1

  float* out0 = (float*)d_out;                      // x_embedded [N,F]
  float* out2 = out0 + (size_t)N * F;               // sigmoid(logits) [N,2]

  init_kernel<<<nzb + 96, 256, 0, stream>>>(ei, flag, deg, cursor, W, W1, wt,
                                            w1t, N, nzb);
  count_kernel<<<(EN + 255) / 256, 256, 0, stream>>>(ei, deg, flag, E, N);
  scan1_kernel<<<nchunks, 256, 0, stream>>>(deg, partial, N);
  scan3_kernel<<<nchunks, 256, 0, stream>>>(deg, partial, row_start, nchunks, N);
  fill_kernel<<<(EN + 255) / 256, 256, 0, stream>>>(ei, row_start, cursor,
                                                    sorted_src, flag, E, N);
  gemm_xp_kernel<<<768, 512, 0, stream>>>(x, wt, a_src, a_dst, xp, alpha_s,
                                          alpha_d, N, ntiles);
  gather_kernel<<<(N + 3) / 4, 256, 0, stream>>>(row_start, sorted_src, alpha_s,
                                                 alpha_d, xp, bias, out0, xe16,
                                                 N);
  mlp_kernel<<<768, 512, 0, stream>>>(x, xe16, w1t, b1, W2, b2, W3, b3, out2, N,
                                      ntiles);
}

// Round 12
// 173.905 us; speedup vs baseline: 1.2955x; 1.2955x over previous
//
#include <hip/hip_runtime.h>

#define F 128
#define LEAK 0.2f

typedef __attribute__((ext_vector_type(8))) short bf16x8;
typedef __attribute__((ext_vector_type(4))) float f32x4;

union FragU { bf16x8 v; unsigned u[4]; };

__device__ inline unsigned f2bf(float f) {
  unsigned u = __float_as_uint(f);
  return (u + 0x7FFFu + ((u >> 16) & 1u)) >> 16;  // RNE
}
__device__ inline unsigned packbf(float lo, float hi) {
  return f2bf(lo) | (f2bf(hi) << 16);
}
__device__ inline float bflo(unsigned u) { return __uint_as_float(u << 16); }
__device__ inline float bfhi(unsigned u) { return __uint_as_float(u & 0xFFFF0000u); }

// fetch (src,dst) for concat([edges, self-loops]) edge i
__device__ inline void edge_sd(const int* ei, int i, int E, int is64, int& s, int& d) {
  if (i < E) {
    if (is64) {
      const long long* e64 = (const long long*)ei;
      s = (int)e64[i]; d = (int)e64[E + i];
    } else {
      s = ei[i]; d = ei[E + i];
    }
  } else {
    s = d = i - E;
  }
}

// ---------- init: zero deg/cursor, probe edge dtype, AND prep weight transposes ----------
// blocks [0, nzb): zero+detect; blocks [nzb, nzb+96): W/W1 -> bf16 [n][k]
__global__ void init_kernel(const int* ei, int* flag, int* deg, int* cursor,
                            const float* __restrict__ W,
                            const float* __restrict__ W1, unsigned* wt,
                            unsigned* w1t, int N, int nzb) {
  if ((int)blockIdx.x < nzb) {
    int i = blockIdx.x * blockDim.x + threadIdx.x;
    if (i < N) { deg[i] = 0; cursor[i] = 0; }
    if (blockIdx.x == 0) {
      __shared__ int any;
      if (threadIdx.x == 0) any = 0;
      __syncthreads();
      for (int k = threadIdx.x; k < 1024; k += blockDim.x)
        if (ei[2 * k + 1] != 0) any = 1;
      __syncthreads();
      if (threadIdx.x == 0) *flag = (any == 0) ? 1 : 0;  // 1 => int64
    }
    return;
  }
  int i = (blockIdx.x - nzb) * 256 + threadIdx.x;
  if (i < 128 * 64) {
    int n = i & 127, k2 = i >> 7;
    wt[n * 64 + k2] =
        packbf(W[(size_t)(2 * k2) * 128 + n], W[(size_t)(2 * k2 + 1) * 128 + n]);
  }
  int j = i - 128 * 64;
  if (j >= 0 && j < 128 * 128) {
    int n = j & 127, k2 = j >> 7;
    w1t[n * 128 + k2] = packbf(W1[(size_t)(2 * k2) * 128 + n],
                               W1[(size_t)(2 * k2 + 1) * 128 + n]);
  }
}

// ---------- count in-degree (incl self-loops) ----------
__global__ void count_kernel(const int* ei, int* deg, const int* flag, int E, int N) {
  int i = blockIdx.x * blockDim.x + threadIdx.x;
  if (i >= E + N) return;
  int s, d;
  edge_sd(ei, i, E, *flag, s, d);
  atomicAdd(&deg[d], 1);
}

// ---------- scan phase 1: per-1024-chunk sums ----------
__global__ void scan1_kernel(const int* deg, int* partial, int N) {
  __shared__ int ts[256];
  int b = blockIdx.x, t = threadIdx.x;
  int base = b * 1024 + t * 4;
  int s = 0;
#pragma unroll
  for (int k = 0; k < 4; ++k) s += (base + k < N) ? deg[base + k] : 0;
  ts[t] = s;
  __syncthreads();
  for (int o = 128; o > 0; o >>= 1) {
    if (t < o) ts[t] += ts[t + o];
    __syncthreads();
  }
  if (t == 0) partial[b] = ts[0];
}

// ---------- scan phase 2+3 merged: each block re-scans chunk sums locally ----------
__global__ void scan3_kernel(const int* deg, const int* partial,
                             int* row_start, int nchunks, int N) {
  __shared__ int ts[256];
  __shared__ int cs[256];
  int b = blockIdx.x, t = threadIdx.x;

  int pv = (t < nchunks) ? partial[t] : 0;
  cs[t] = pv;
  __syncthreads();
  for (int o = 1; o < 256; o <<= 1) {
    int add = (t >= o) ? cs[t - o] : 0;
    __syncthreads();
    cs[t] += add;
    __syncthreads();
  }
  if (b == 0 && t == 0) row_start[N] = cs[nchunks - 1];  // total = E + N
  int chunk_off_b = cs[b] - partial[b];  // exclusive prefix of chunk b

  int base = b * 1024 + t * 4;
  int v[4];
#pragma unroll
  for (int k = 0; k < 4; ++k) v[k] = (base + k < N) ? deg[base + k] : 0;
  int p1 = v[0], p2 = p1 + v[1], p3 = p2 + v[2], sum = p3 + v[3];
  ts[t] = sum;
  __syncthreads();
  for (int o = 1; o < 256; o <<= 1) {
    int add = (t >= o) ? ts[t - o] : 0;
    __syncthreads();
    ts[t] += add;
    __syncthreads();
  }
  int off = chunk_off_b + ts[t] - sum;
  int ex[4] = {0, p1, p2, p3};
#pragma unroll
  for (int k = 0; k < 4; ++k)
    if (base + k < N) row_start[base + k] = off + ex[k];
}

// ---------- fill sorted_src buckets ----------
__global__ void fill_kernel(const int* ei, const int* row_start, int* cursor,
                            int* sorted_src, const int* flag, int E, int N) {
  int i = blockIdx.x * blockDim.x + threadIdx.x;
  if (i >= E + N) return;
  int s, d;
  edge_sd(ei, i, E, *flag, s, d);
  int p = atomicAdd(&cursor[d], 1);
  sorted_src[row_start[d] + p] = s;
}

// ---------- xp = x @ W via bf16 MFMA; B staged in LDS; xp bf16 via LDS bounce ----------
// 512 threads = 8 waves, wave owns 16 rows; grid-stride over 128-row tiles.
__global__ __launch_bounds__(512) void gemm_xp_kernel(
    const float* __restrict__ x, const unsigned* __restrict__ wt,
    const float* __restrict__ a_src, const float* __restrict__ a_dst,
    unsigned short* __restrict__ xp, float* __restrict__ alpha_s,
    float* __restrict__ alpha_d, int N, int ntiles) {
  __shared__ char WtL[128 * 256];   // [n][k] bf16 swizzled, 32KB
  __shared__ char stage[8 * 4096];  // per-wave 16 rows x 256B, swizzled
  const int tid = threadIdx.x;
  const int w = tid >> 6, l = tid & 63;
  const int lr = l & 15, lg = l >> 4;
  char* st = stage + w * 4096;

  // stage whole Wt (bf16 [n][128k]) into LDS, swizzled
  for (int c = tid; c < 2048; c += 512) {
    int n = c >> 4, q = c & 15;
    uint4 v = *(const uint4*)(wt + n * 64 + q * 4);
    *(uint4*)(WtL + n * 256 + ((q * 16) ^ ((n & 7) << 4))) = v;
  }

  float asv[8], adv[8];
#pragma unroll
  for (int f = 0; f < 8; ++f) {
    asv[f] = a_src[f * 16 + lr];
    adv[f] = a_dst[f * 16 + lr];
  }
  __syncthreads();

  for (int t = blockIdx.x; t < ntiles; t += gridDim.x) {
    const int rbase = t * 128 + w * 16;
    const int rc = min(rbase + lr, N - 1);
    const float* xrow = x + (size_t)rc * 128;

    FragU a[4];
#pragma unroll
    for (int ks = 0; ks < 4; ++ks) {
      float4 p0 = *(const float4*)(xrow + ks * 32 + lg * 8);
      float4 p1 = *(const float4*)(xrow + ks * 32 + lg * 8 + 4);
      a[ks].u[0] = packbf(p0.x, p0.y); a[ks].u[1] = packbf(p0.z, p0.w);
      a[ks].u[2] = packbf(p1.x, p1.y); a[ks].u[3] = packbf(p1.z, p1.w);
    }

    f32x4 acc[8];
#pragma unroll
    for (int f = 0; f < 8; ++f) acc[f] = (f32x4){0.f, 0.f, 0.f, 0.f};

#pragma unroll
    for (int ks = 0; ks < 4; ++ks) {
#pragma unroll
      for (int f = 0; f < 8; ++f) {
        int n = f * 16 + lr;
        FragU bfr;
        bfr.v = *(const bf16x8*)(WtL + n * 256 +
                                 ((ks * 64 + lg * 16) ^ ((n & 7) << 4)));
        acc[f] = __builtin_amdgcn_mfma_f32_16x16x32_bf16(a[ks].v, bfr.v,
                                                         acc[f], 0, 0, 0);
      }
    }

    // fused alpha reductions (fp32, from acc directly)
#pragma unroll
    for (int r = 0; r < 4; ++r) {
      int orow = rbase + lg * 4 + r;
      float ps = 0.f, pd = 0.f;
#pragma unroll
      for (int f = 0; f < 8; ++f) {
        ps = fmaf(acc[f][r], asv[f], ps);
        pd = fmaf(acc[f][r], adv[f], pd);
      }
#pragma unroll
      for (int m = 1; m < 16; m <<= 1) {
        ps += __shfl_xor(ps, m);
        pd += __shfl_xor(pd, m);
      }
      if (orow < N && lr == 0) alpha_s[orow] = ps;
      if (orow < N && lr == 1) alpha_d[orow] = pd;
    }

    // stage acc -> per-wave LDS (bf16, XOR-swizzled rows), then coalesced store
#pragma unroll
    for (int f = 0; f < 8; ++f) {
      int colb = (f * 16 + lr) * 2;
#pragma unroll
      for (int r = 0; r < 4; ++r) {
        int row = lg * 4 + r;
        *(unsigned short*)(st + row * 256 + (colb ^ ((row & 7) << 4))) =
            (unsigned short)f2bf(acc[f][r]);
      }
    }
#pragma unroll
    for (int it = 0; it < 4; ++it) {
      int off = it * 1024 + l * 16;
      int row = off >> 8, colb = off & 255;
      int4 v = *(const int4*)(st + row * 256 + (colb ^ ((row & 7) << 4)));
      int grow = rbase + row;
      if (grow < N) *(int4*)((char*)xp + (size_t)grow * 256 + colb) = v;
    }
  }
}

// ---------- gather: one wave per dst node; in-register softmax; half-wave 2-edge
// feature accumulation (each 32-lane half owns one edge, 8B/lane) ----------
__global__ __launch_bounds__(256) void gather_kernel(
    const int* __restrict__ row_start, const int* __restrict__ sorted_src,
    const float* __restrict__ alpha_s, const float* __restrict__ alpha_d,
    const unsigned short* __restrict__ xp, const float* __restrict__ bias,
    float* __restrict__ out0, int N) {
  int wid = blockIdx.x * 4 + (threadIdx.x >> 6);
  int lane = threadIdx.x & 63;
  if (wid >= N) return;
  int rs = row_start[wid], re = row_start[wid + 1];
  int deg = re - rs;
  float ad = alpha_d[wid];

  if (deg <= 64) {
    const int half = lane >> 5;  // which edge of the pair
    const int hl = lane & 31;    // lane within half: features hl*4..+3

    // lane j owns edge j: score, wave softmax (w_reg = 0 for lanes >= deg)
    int src_reg = 0;
    float e = -INFINITY;
    if (lane < deg) {
      src_reg = sorted_src[rs + lane];
      e = alpha_s[src_reg] + ad;
      e = (e >= 0.f) ? e : LEAK * e;
    }
    float m = e;
#pragma unroll
    for (int o = 32; o > 0; o >>= 1) m = fmaxf(m, __shfl_xor(m, o));
    float ex = (lane < deg) ? expf(e - m) : 0.f;
    float lsum = ex;
#pragma unroll
    for (int o = 32; o > 0; o >>= 1) lsum += __shfl_xor(lsum, o);
    float w_reg = ex / lsum;

    float c0 = 0.f, c1 = 0.f, c2 = 0.f, c3 = 0.f;
    int j = 0;
    for (; j + 3 < deg; j += 4) {  // 4 edges: 2 per half, 2 loads in flight
      int jj0 = j + half, jj1 = j + 2 + half;
      int s0 = __shfl(src_reg, jj0), s1 = __shfl(src_reg, jj1);
      float w0 = __shfl(w_reg, jj0), w1 = __shfl(w_reg, jj1);
      uint2 u0 = *(const uint2*)(xp + (size_t)s0 * 128 + hl * 4);
      uint2 u1 = *(const uint2*)(xp + (size_t)s1 * 128 + hl * 4);
      c0 = fmaf(w0, bflo(u0.x), c0); c1 = fmaf(w0, bfhi(u0.x), c1);
      c2 = fmaf(w0, bflo(u0.y), c2); c3 = fmaf(w0, bfhi(u0.y), c3);
      c0 = fmaf(w1, bflo(u1.x), c0); c1 = fmaf(w1, bfhi(u1.x), c1);
      c2 = fmaf(w1, bflo(u1.y), c2); c3 = fmaf(w1, bfhi(u1.y), c3);
    }
    for (; j < deg; j += 2) {  // tail: jj <= 63 always (j even, j < deg <= 64)
      int jj = j + half;
      int s0 = __shfl(src_reg, jj);
      float w0 = __shfl(w_reg, jj);  // 0 when jj >= deg
      uint2 u0 = *(const uint2*)(xp + (size_t)s0 * 128 + hl * 4);
      c0 = fmaf(w0, bflo(u0.x), c0); c1 = fmaf(w0, bfhi(u0.x), c1);
      c2 = fmaf(w0, bflo(u0.y), c2); c3 = fmaf(w0, bfhi(u0.y), c3);
    }
    // combine halves, half 0 stores float4
    c0 += __shfl_xor(c0, 32); c1 += __shfl_xor(c1, 32);
    c2 += __shfl_xor(c2, 32); c3 += __shfl_xor(c3, 32);
    if (half == 0) {
      float4 bv = *(const float4*)(bias + hl * 4);
      *(float4*)(out0 + (size_t)wid * F + hl * 4) =
          make_float4(c0 + bv.x, c1 + bv.y, c2 + bv.z, c3 + bv.w);
    }
  } else {
    // rare fallback: strided softmax stats, then uniform per-edge loop
    float a0 = 0.f, a1 = 0.f;
    float m = -INFINITY;
    for (int j = lane; j < deg; j += 64) {
      float e = alpha_s[sorted_src[rs + j]] + ad;
      e = (e >= 0.f) ? e : LEAK * e;
      m = fmaxf(m, e);
    }
#pragma unroll
    for (int o = 32; o > 0; o >>= 1) m = fmaxf(m, __shfl_xor(m, o));
    float lsum = 0.f;
    for (int j = lane; j < deg; j += 64) {
      float e = alpha_s[sorted_src[rs + j]] + ad;
      e = (e >= 0.f) ? e : LEAK * e;
      lsum += expf(e - m);
    }
#pragma unroll
    for (int o = 32; o > 0; o >>= 1) lsum += __shfl_xor(lsum, o);
    float inv = 1.f / lsum;
    for (int j = 0; j < deg; ++j) {
      int s0 = sorted_src[rs + j];
      float e = alpha_s[s0] + ad;
      e = (e >= 0.f) ? e : LEAK * e;
      float w0 = expf(e - m) * inv;
      unsigned u0 = *(const unsigned*)(xp + (size_t)s0 * 128 + lane * 2);
      a0 = fmaf(w0, bflo(u0), a0); a1 = fmaf(w0, bfhi(u0), a1);
    }
    float2 bv = *(const float2*)(bias + lane * 2);
    *(float2*)(out0 + (size_t)wid * F + lane * 2) =
        make_float2(a0 + bv.x, a1 + bv.y);
  }
}

// ---------- fused MLP via bf16 MFMA; W1 staged per-K-half in LDS ----------
// 512 threads = 8 waves; 128-row tiles grid-stride; wave w owns rows w*16..+15.
__global__ __launch_bounds__(512) void mlp_kernel(
    const float* __restrict__ x, const float* __restrict__ xemb,
    const unsigned* __restrict__ w1t, const float* __restrict__ b1,
    const float* __restrict__ W2, const float* __restrict__ b2,
    const float* __restrict__ W3, const float* __restrict__ b3,
    float* __restrict__ out2, int N, int ntiles) {
  __shared__ char W1L[128 * 256];  // [n][one K-half] bf16 swizzled, 32KB
  __shared__ char W2t[16 * 256];   // [n][k] bf16 swizzled, 4KB
  __shared__ char h1s[128 * 256];  // [row][k] bf16 swizzled, 32KB (per-wave regions)
  const int tid = threadIdx.x;

  for (int idx = tid; idx < 16 * 64; idx += 512) {
    int n = idx & 15, k = (idx >> 4) * 2;
    unsigned p = packbf(W2[(size_t)k * 16 + n], W2[(size_t)(k + 1) * 16 + n]);
    *(unsigned*)(W2t + n * 256 + ((k * 2) ^ ((n & 7) << 4))) = p;
  }

  const int w = tid >> 6, l = tid & 63;
  const int lr = l & 15, lg = l >> 4;
  float b1v[8];
#pragma unroll
  for (int f = 0; f < 8; ++f) b1v[f] = b1[f * 16 + lr];
  const float b2v = b2[lr];
  const float w30 = W3[lr * 2 + 0], w31 = W3[lr * 2 + 1];
  const float b30 = b3[0], b31 = b3[1];

  for (int t = blockIdx.x; t < ntiles; t += gridDim.x) {
    const int rbase = t * 128 + w * 16;
    const int rc = min(rbase + lr, N - 1);
    const float* xrow = x + (size_t)rc * 128;
    const float* erow = xemb + (size_t)rc * 128;

    f32x4 acc[8];
#pragma unroll
    for (int f = 0; f < 8; ++f) acc[f] = (f32x4){0.f, 0.f, 0.f, 0.f};

#pragma unroll
    for (int hh = 0; hh < 2; ++hh) {
      // stage K-half hh of W1 into LDS (from pre-transposed bf16 w1t)
      __syncthreads();  // prev readers done (also covers prev tile's reads)
      for (int c = tid; c < 2048; c += 512) {
        int n = c >> 4, q = c & 15;
        uint4 v = *(const uint4*)(w1t + n * 128 + hh * 64 + q * 4);
        *(uint4*)(W1L + n * 256 + ((q * 16) ^ ((n & 7) << 4))) = v;
      }
      __syncthreads();

      // pack this half's A fragments (hh=0: x, hh=1: relu(xemb))
      FragU a[4];
#pragma unroll
      for (int ks = 0; ks < 4; ++ks) {
        const float* src = (hh == 0) ? (xrow + ks * 32 + lg * 8)
                                     : (erow + ks * 32 + lg * 8);
        float4 p0 = *(const float4*)(src);
        float4 p1 = *(const float4*)(src + 4);
        if (hh == 1) {
          p0.x = fmaxf(p0.x, 0.f); p0.y = fmaxf(p0.y, 0.f);
          p0.z = fmaxf(p0.z, 0.f); p0.w = fmaxf(p0.w, 0.f);
          p1.x = fmaxf(p1.x, 0.f); p1.y = fmaxf(p1.y, 0.f);
          p1.z = fmaxf(p1.z, 0.f); p1.w = fmaxf(p1.w, 0.f);
        }
        a[ks].u[0] = packbf(p0.x, p0.y); a[ks].u[1] = packbf(p0.z, p0.w);
        a[ks].u[2] = packbf(p1.x, p1.y); a[ks].u[3] = packbf(p1.z, p1.w);
      }

#pragma unroll
      for (int ks = 0; ks < 4; ++ks) {
#pragma unroll
        for (int f = 0; f < 8; ++f) {
          int n = f * 16 + lr;
          FragU bfr;
          bfr.v = *(const bf16x8*)(W1L + n * 256 +
                                   ((ks * 64 + lg * 16) ^ ((n & 7) << 4)));
          acc[f] = __builtin_amdgcn_mfma_f32_16x16x32_bf16(a[ks].v, bfr.v,
                                                           acc[f], 0, 0, 0);
        }
      }
    }

    // h1 = relu(acc + b1) -> per-wave LDS region (bf16, swizzled)
#pragma unroll
    for (int f = 0; f < 8; ++f) {
      int col = f * 16 + lr;
#pragma unroll
      for (int r = 0; r < 4; ++r) {
        int hrow = w * 16 + lg * 4 + r;
        float v = fmaxf(acc[f][r] + b1v[f], 0.f);
        *(unsigned short*)(h1s + hrow * 256 + ((col * 2) ^ ((hrow & 7) << 4))) =
            (unsigned short)f2bf(v);
      }
    }

    // ---- layer 2: wave's 16 rows x 16 cols, K=128 (wave-local LDS) ----
    f32x4 acc2 = (f32x4){0.f, 0.f, 0.f, 0.f};
#pragma unroll
    for (int ks = 0; ks < 4; ++ks) {
      int hrow = w * 16 + lr;
      FragU af, bfr;
      af.v = *(const bf16x8*)(h1s + hrow * 256 +
                              ((ks * 64 + lg * 16) ^ ((hrow & 7) << 4)));
      bfr.v = *(const bf16x8*)(W2t + lr * 256 +
                               ((ks * 64 + lg * 16) ^ ((lr & 7) << 4)));
      acc2 = __builtin_amdgcn_mfma_f32_16x16x32_bf16(af.v, bfr.v, acc2, 0, 0, 0);
    }

    // ---- layer 3 + sigmoid: quarter-wave shuffle reduce over 16 cols ----
#pragma unroll
    for (int r = 0; r < 4; ++r) {
      float h2 = fmaxf(acc2[r] + b2v, 0.f);
      float t0 = h2 * w30, t1 = h2 * w31;
#pragma unroll
      for (int m = 1; m < 16; m <<= 1) {
        t0 += __shfl_xor(t0, m);
        t1 += __shfl_xor(t1, m);
      }
      int orow = rbase + lg * 4 + r;
      if (orow < N && lr < 2) {
        float s = (lr == 0) ? (t0 + b30) : (t1 + b31);
        out2[(size_t)orow * 2 + lr] = 1.f / (1.f + expf(-s));
      }
    }
  }
}

// ---------- launch ----------
extern "C" void kernel_launch(void* const* d_in, const int* in_sizes, int n_in,
                              void* d_out, int out_size, void* d_ws,
                              size_t ws_size, hipStream_t stream) {
  const float* x     = (const float*)d_in[0];
  const int*   ei    = (const int*)d_in[1];
  const float* W     = (const float*)d_in[2];
  const float* a_src = (const float*)d_in[3];
  const float* a_dst = (const float*)d_in[4];
  const float* bias  = (const float*)d_in[5];
  const float* W1    = (const float*)d_in[6];
  const float* b1    = (const float*)d_in[7];
  const float* W2    = (const float*)d_in[8];
  const float* b2    = (const float*)d_in[9];
  const float* W3    = (const float*)d_in[10];
  const float* b3    = (const float*)d_in[11];

  const int N = in_sizes[0] / F;
  const int E = in_sizes[1] / 2;
  const int EN = E + N;
  const int nchunks = (N + 1023) / 1024;
  const int ntiles = (N + 127) / 128;
  const int nzb = (N + 255) / 256;

  float* ws = (float*)d_ws;
  unsigned short* xp = (unsigned short*)ws;     // N*128 bf16 (= N*64 floats)
  float* alpha_s  = ws + (size_t)N * 64;        // N
  float* alpha_d  = alpha_s + N;                // N
  unsigned* wt    = (unsigned*)(alpha_d + N);   // 128*64
  unsigned* w1t   = wt + 128 * 64;              // 128*128
  int* deg        = (int*)(w1t + 128 * 128);    // N
  int* row_start  = deg + N;                    // N+1
  int* cursor     = row_start + N + 1;          // N
  int* partial    = cursor + N;                 // 256
  int* sorted_src = partial + 256;              // EN
  int* flag       = sorted_src + EN;            // 1

  float* out0 = (float*)d_out;                  // x_embedded [N,F]
  float* out2 = out0 + (size_t)N * F;           // sigmoid(logits) [N,2]

  init_kernel<<<nzb + 96, 256, 0, stream>>>(ei, flag, deg, cursor, W, W1, wt,
                                            w1t, N, nzb);
  count_kernel<<<(EN + 255) / 256, 256, 0, stream>>>(ei, deg, flag, E, N);
  scan1_kernel<<<nchunks, 256, 0, stream>>>(deg, partial, N);
  scan3_kernel<<<nchunks, 256, 0, stream>>>(deg, partial, row_start, nchunks, N);
  fill_kernel<<<(EN + 255) / 256, 256, 0, stream>>>(ei, row_start, cursor,
                                                    sorted_src, flag, E, N);
  gemm_xp_kernel<<<512, 512, 0, stream>>>(x, wt, a_src, a_dst, xp, alpha_s,
                                          alpha_d, N, ntiles);
  gather_kernel<<<(N + 3) / 4, 256, 0, stream>>>(row_start, sorted_src, alpha_s,
                                                 alpha_d, xp, bias, out0, N);
  mlp_kernel<<<512, 512, 0, stream>>>(x, out0, w1t, b1, W2, b2, W3, b3, out2, N,
                                      ntiles);
}